// Round 9
// baseline (105.642 us; speedup 1.0000x reference)
//
#include <hip/hip_runtime.h>
#include <hip/hip_bf16.h>

#define NN 512
#define FIN 128
#define HH 4
#define DD 64
#define SW 68   // permuted/padded e-width: 17 groups x 4
// lrelu(z) = 0.6*z + 0.4*|z|; a.lrelu folded: 0.6*(a.zi+a.zj) + sum_g sgn_g*|azi+azj|

// ws layout (floats):
//  h_ws   [8][512][64]        262144 @ 0
//  azi_ws [8][512][68]        278528 @ 262144   (|a|-scaled, e-permuted, zi+Wcb)
//  azjB   [8][8][17][64][4]   278528 @ 540672   (blocked: jt-tile, group, j, 4 slots)
//  adi_ws [8][512]            4096   @ 819200   (0.6 * sum_e a*zi')
//  adj_ws [8][512]            4096   @ 823296

// ---------------------------------------------------------------------------
// proj: h = x@Wp + bp ; zi' = h@W1^T + Wcb ; zj = h@W2^T ; adi/adj dots ;
// sign-partition scatter of azi (row-major) and azjB (blocked). 512 x 256.
// ---------------------------------------------------------------------------
__global__ __launch_bounds__(256) void proj_kernel(
    const float* __restrict__ x, const float* __restrict__ Wp,
    const float* __restrict__ bp, const float* __restrict__ Wc,
    const float* __restrict__ Wcb, const float* __restrict__ a,
    float* __restrict__ h_ws, float* __restrict__ azi_ws, float* __restrict__ azjB,
    float* __restrict__ adi_ws, float* __restrict__ adj_ws)
{
    int blk = blockIdx.x;
    int bh = blk >> 6;
    int n0 = (blk & 63) << 3;
    int b = bh >> 2, hh = bh & 3;

    __shared__ float xs[8 * FIN];
    __shared__ float hs[8][DD];
    __shared__ float Wcs[DD][2 * DD + 1];
    __shared__ float tzj[8][DD + 1];
    __shared__ int   slot2e[SW];
    __shared__ float slot2pa[SW];

    int t = threadIdx.x;

    ((float4*)xs)[t] = ((const float4*)(x + ((size_t)b * NN + n0) * FIN))[t];
    {
        const float4* wg = (const float4*)(Wc + (size_t)hh * DD * 2 * DD);
        #pragma unroll
        for (int k = 0; k < 8; ++k) {
            int idx = t + 256 * k;
            int r = idx >> 5, c4 = (idx & 31) * 4;
            float4 v = wg[idx];
            Wcs[r][c4] = v.x; Wcs[r][c4 + 1] = v.y;
            Wcs[r][c4 + 2] = v.z; Wcs[r][c4 + 3] = v.w;
        }
    }
    __syncthreads();

    int e = t & 63, w = t >> 6;            // rows w, w+4
    const float* Wph = Wp + (size_t)hh * FIN * DD;
    float bpv = bp[hh * DD + e];
    float acc0 = bpv, acc1 = bpv;
    #pragma unroll 8
    for (int i = 0; i < FIN; ++i) {
        float wv = Wph[i * DD + e];
        acc0 = fmaf(xs[w * FIN + i], wv, acc0);
        acc1 = fmaf(xs[(w + 4) * FIN + i], wv, acc1);
    }
    hs[w][e] = acc0; hs[w + 4][e] = acc1;
    float* hg = h_ws + ((size_t)bh * NN + n0) * DD;
    hg[w * DD + e] = acc0; hg[(w + 4) * DD + e] = acc1;
    __syncthreads();

    float zb = Wcb[hh * DD + e];
    float zi0 = zb, zi1 = zb, zj0 = 0.f, zj1 = 0.f;
    #pragma unroll 8
    for (int d2 = 0; d2 < DD; ++d2) {
        float w1 = Wcs[e][d2];
        float w2 = Wcs[e][DD + d2];
        float h0 = hs[w][d2], h1 = hs[w + 4][d2];
        zi0 = fmaf(h0, w1, zi0); zi1 = fmaf(h1, w1, zi1);
        zj0 = fmaf(h0, w2, zj0); zj1 = fmaf(h1, w2, zj1);
    }
    tzj[w][e] = zj0; tzj[w + 4][e] = zj1;

    float av = a[hh * DD + e];
    float p0 = av * zi0, p1 = av * zi1, q0 = av * zj0, q1 = av * zj1;
    #pragma unroll
    for (int off = 32; off; off >>= 1) {
        p0 += __shfl_xor(p0, off); p1 += __shfl_xor(p1, off);
        q0 += __shfl_xor(q0, off); q1 += __shfl_xor(q1, off);
    }
    if (e == 0) {
        adi_ws[bh * NN + n0 + w]     = 0.6f * p0;
        adi_ws[bh * NN + n0 + w + 4] = 0.6f * p1;
        adj_ws[bh * NN + n0 + w]     = 0.6f * q0;
        adj_ws[bh * NN + n0 + w + 4] = 0.6f * q1;
    }

    unsigned long long mask = __ballot(av >= 0.f);
    int np = __popcll(mask);
    int GP = (np + 3) >> 2;
    int below = __popcll(mask & ((1ull << e) - 1ull));
    int slot = (av >= 0.f) ? below : (4 * GP + (e - below));
    float pav = __builtin_fabsf(av);

    float* azib = azi_ws + ((size_t)bh * NN + n0) * SW;
    azib[w * SW + slot]       = pav * zi0;
    azib[(w + 4) * SW + slot] = pav * zi1;
    if (w == 0) { slot2e[slot] = e; slot2pa[slot] = pav; }
    int p1c = 4 * GP - np;
    if (e < 4) {
        int psl = (e < p1c) ? (np + e) : (4 * GP + 64 - np + (e - p1c));
        azib[w * SW + psl] = 0.f; azib[(w + 4) * SW + psl] = 0.f;
        if (w == 0) { slot2e[psl] = 0; slot2pa[psl] = 0.f; }
    }
    __syncthreads();

    // azjB blocked write: [bh][jt][g][jl] float4 (4 consecutive slots per j)
    if (t < 8 * 17) {
        int r = t / 17, g = t % 17;
        float4 v;
        v.x = slot2pa[4 * g + 0] * tzj[r][slot2e[4 * g + 0]];
        v.y = slot2pa[4 * g + 1] * tzj[r][slot2e[4 * g + 1]];
        v.z = slot2pa[4 * g + 2] * tzj[r][slot2e[4 * g + 2]];
        v.w = slot2pa[4 * g + 3] * tzj[r][slot2e[4 * g + 3]];
        int jt = n0 >> 6, jl = (n0 & 63) + r;
        ((float4*)azjB)[((size_t)(bh * 8 + jt) * 17 + g) * 64 + jl] = v;
    }
}

// ---------------------------------------------------------------------------
// attn2: 1 i-row per wave, Ti=4/block, full j (online softmax), direct out.
// grid = 8bh x 128it = 1024 blocks x 256 thr. ONE barrier total; operands
// streamed from global (azjB: 17 coalesced b128; h: 64 coalesced b32).
// ---------------------------------------------------------------------------
__global__ __launch_bounds__(256, 4) void attn2(
    const float* __restrict__ h_ws, const float* __restrict__ azi_ws,
    const float* __restrict__ azjB, const float* __restrict__ adi_ws,
    const float* __restrict__ adj_ws, const float* __restrict__ a,
    const float* __restrict__ bias_param, float* __restrict__ out)
{
    int blk = blockIdx.x;
    int bh = blk >> 7, it = blk & 127;
    int i0 = it << 2;
    int b = bh >> 2, hh = bh & 3;

    __shared__ float azis[4 * SW];     // 1.1 KB
    __shared__ float pbuf[4][64];      // 1 KB (wave-private)

    int t = threadIdx.x, lane = t & 63, w = t >> 6;

    if (t < 68)
        ((float4*)azis)[t] =
            ((const float4*)(azi_ws + ((size_t)bh * NN + i0) * SW))[t];

    // group signs from ballot of a (lane = e)
    float av_e = a[hh * DD + lane];
    unsigned long long mask = __ballot(av_e >= 0.f);
    int GP = (__popcll(mask) + 3) >> 2;

    float adiv = adi_ws[bh * NN + i0 + w];     // wave-uniform
    float mrun = -1e30f, srun = 0.f;
    float pv0 = 0.f, pv1 = 0.f, pv2 = 0.f, pv3 = 0.f;

    __syncthreads();

    const float* arow = azis + w * SW;
    for (int jt = 0; jt < 8; ++jt) {
        // ---- scores: 17 coalesced b128 azj loads, uniform b128 azi reads ----
        const float4* ajB = (const float4*)azjB
                          + ((size_t)(bh * 8 + jt) * 17) * 64 + lane;
        float adjv = adj_ws[bh * NN + jt * 64 + lane];
        float c0 = 0.f, c1 = 0.f, c2 = 0.f, c3 = 0.f;
        #pragma unroll
        for (int k = 0; k < 17; ++k) {
            float4 aj = ajB[k * 64];                       // global b128
            float4 zi4 = *(const float4*)(arow + 4 * k);   // uniform ds b128
            float s = (k < GP) ? 0.4f : -0.4f;
            c0 = fmaf(s, __builtin_fabsf(zi4.x + aj.x), c0);
            c1 = fmaf(s, __builtin_fabsf(zi4.y + aj.y), c1);
            c2 = fmaf(s, __builtin_fabsf(zi4.z + aj.z), c2);
            c3 = fmaf(s, __builtin_fabsf(zi4.w + aj.w), c3);
        }
        float ev = adiv + adjv + ((c0 + c1) + (c2 + c3));

        // ---- online softmax (wave reduce) ----
        float mt = ev;
        #pragma unroll
        for (int off = 32; off; off >>= 1) mt = fmaxf(mt, __shfl_xor(mt, off));
        float m_new = fmaxf(mrun, mt);
        float sc = __expf(mrun - m_new);
        float p = __expf(ev - m_new);
        float psum = p;
        #pragma unroll
        for (int off = 32; off; off >>= 1) psum += __shfl_xor(psum, off);
        srun = srun * sc + psum;
        mrun = m_new;
        pbuf[w][lane] = p;

        // ---- PV: h streamed from global (coalesced b32), p uniform b128 ----
        pv0 *= sc; pv1 *= sc; pv2 *= sc; pv3 *= sc;
        const float4* pr = (const float4*)pbuf[w];
        const float* hb = h_ws + ((size_t)bh * NN + jt * 64) * DD + lane;
        #pragma unroll
        for (int k = 0; k < 16; ++k) {
            float4 p4 = pr[k];
            pv0 = fmaf(p4.x, hb[(4 * k + 0) * DD], pv0);
            pv1 = fmaf(p4.y, hb[(4 * k + 1) * DD], pv1);
            pv2 = fmaf(p4.z, hb[(4 * k + 2) * DD], pv2);
            pv3 = fmaf(p4.w, hb[(4 * k + 3) * DD], pv3);
        }
    }

    float acc = (pv0 + pv1) + (pv2 + pv3);
    out[((size_t)b * NN + i0 + w) * (HH * DD) + hh * DD + lane] =
        acc / srun + bias_param[hh * DD + lane];
}

extern "C" void kernel_launch(void* const* d_in, const int* in_sizes, int n_in,
                              void* d_out, int out_size, void* d_ws, size_t ws_size,
                              hipStream_t stream) {
    const float* x    = (const float*)d_in[0];
    const float* Wp   = (const float*)d_in[1];
    const float* bp   = (const float*)d_in[2];
    const float* Wc   = (const float*)d_in[3];
    const float* Wcb  = (const float*)d_in[4];
    const float* a    = (const float*)d_in[5];
    const float* bpar = (const float*)d_in[6];
    float* out = (float*)d_out;

    float* ws     = (float*)d_ws;
    float* h_ws   = ws;
    float* azi_ws = ws + 262144;
    float* azjB   = ws + 540672;
    float* adi_ws = ws + 819200;
    float* adj_ws = ws + 823296;

    proj_kernel<<<dim3(512), dim3(256), 0, stream>>>(
        x, Wp, bp, Wc, Wcb, a, h_ws, azi_ws, azjB, adi_ws, adj_ws);
    attn2<<<dim3(1024), dim3(256), 0, stream>>>(
        h_ws, azi_ws, azjB, adi_ws, adj_ws, a, bpar, out);
}

// Round 11
// 47.061 us; speedup vs baseline: 2.2448x; 2.2448x over previous
//
#include <hip/hip_runtime.h>
#include <hip/hip_bf16.h>

#define NN 512
#define FIN 128
#define HH 4
#define DD 64
#define SW 68   // permuted/padded e-width: 17 groups x 4
// lrelu(z) = 0.6*z + 0.4*|z|; a.lrelu folded: 0.6*(a.zi+a.zj) + sum_g sgn_g*|azi+azj|

// ws layout (floats):
//  h_ws   [8][512][64]        262144  @ 0
//  azi_ws [8][512][68]        278528  @ 262144   (|a|-scaled, e-permuted, zi+Wcb)
//  azjB   [8][8][17][64][4]   278528  @ 540672   (blocked: js-tile, group, j, 4 slots)
//  adi_ws [8][512]            4096    @ 819200   (0.6 * sum_e a*zi')
//  adj_ws [8][512]            4096    @ 823296
//  pacc   [8][8][512][64]     2097152 @ 827392
//  pm     [8][4096]           32768   @ 2924544
//  ps     [8][4096]           32768   @ 2957312

// ---------------------------------------------------------------------------
// proj: unchanged (validated r9). 512 blocks x 256.
// ---------------------------------------------------------------------------
__global__ __launch_bounds__(256) void proj_kernel(
    const float* __restrict__ x, const float* __restrict__ Wp,
    const float* __restrict__ bp, const float* __restrict__ Wc,
    const float* __restrict__ Wcb, const float* __restrict__ a,
    float* __restrict__ h_ws, float* __restrict__ azi_ws, float* __restrict__ azjB,
    float* __restrict__ adi_ws, float* __restrict__ adj_ws)
{
    int blk = blockIdx.x;
    int bh = blk >> 6;
    int n0 = (blk & 63) << 3;
    int b = bh >> 2, hh = bh & 3;

    __shared__ float xs[8 * FIN];
    __shared__ float hs[8][DD];
    __shared__ float Wcs[DD][2 * DD + 1];
    __shared__ float tzj[8][DD + 1];
    __shared__ int   slot2e[SW];
    __shared__ float slot2pa[SW];

    int t = threadIdx.x;

    ((float4*)xs)[t] = ((const float4*)(x + ((size_t)b * NN + n0) * FIN))[t];
    {
        const float4* wg = (const float4*)(Wc + (size_t)hh * DD * 2 * DD);
        #pragma unroll
        for (int k = 0; k < 8; ++k) {
            int idx = t + 256 * k;
            int r = idx >> 5, c4 = (idx & 31) * 4;
            float4 v = wg[idx];
            Wcs[r][c4] = v.x; Wcs[r][c4 + 1] = v.y;
            Wcs[r][c4 + 2] = v.z; Wcs[r][c4 + 3] = v.w;
        }
    }
    __syncthreads();

    int e = t & 63, w = t >> 6;            // rows w, w+4
    const float* Wph = Wp + (size_t)hh * FIN * DD;
    float bpv = bp[hh * DD + e];
    float acc0 = bpv, acc1 = bpv;
    #pragma unroll 8
    for (int i = 0; i < FIN; ++i) {
        float wv = Wph[i * DD + e];
        acc0 = fmaf(xs[w * FIN + i], wv, acc0);
        acc1 = fmaf(xs[(w + 4) * FIN + i], wv, acc1);
    }
    hs[w][e] = acc0; hs[w + 4][e] = acc1;
    float* hg = h_ws + ((size_t)bh * NN + n0) * DD;
    hg[w * DD + e] = acc0; hg[(w + 4) * DD + e] = acc1;
    __syncthreads();

    float zb = Wcb[hh * DD + e];
    float zi0 = zb, zi1 = zb, zj0 = 0.f, zj1 = 0.f;
    #pragma unroll 8
    for (int d2 = 0; d2 < DD; ++d2) {
        float w1 = Wcs[e][d2];
        float w2 = Wcs[e][DD + d2];
        float h0 = hs[w][d2], h1 = hs[w + 4][d2];
        zi0 = fmaf(h0, w1, zi0); zi1 = fmaf(h1, w1, zi1);
        zj0 = fmaf(h0, w2, zj0); zj1 = fmaf(h1, w2, zj1);
    }
    tzj[w][e] = zj0; tzj[w + 4][e] = zj1;

    float av = a[hh * DD + e];
    float p0 = av * zi0, p1 = av * zi1, q0 = av * zj0, q1 = av * zj1;
    #pragma unroll
    for (int off = 32; off; off >>= 1) {
        p0 += __shfl_xor(p0, off); p1 += __shfl_xor(p1, off);
        q0 += __shfl_xor(q0, off); q1 += __shfl_xor(q1, off);
    }
    if (e == 0) {
        adi_ws[bh * NN + n0 + w]     = 0.6f * p0;
        adi_ws[bh * NN + n0 + w + 4] = 0.6f * p1;
        adj_ws[bh * NN + n0 + w]     = 0.6f * q0;
        adj_ws[bh * NN + n0 + w + 4] = 0.6f * q1;
    }

    unsigned long long mask = __ballot(av >= 0.f);
    int np = __popcll(mask);
    int GP = (np + 3) >> 2;
    int below = __popcll(mask & ((1ull << e) - 1ull));
    int slot = (av >= 0.f) ? below : (4 * GP + (e - below));
    float pav = __builtin_fabsf(av);

    float* azib = azi_ws + ((size_t)bh * NN + n0) * SW;
    azib[w * SW + slot]       = pav * zi0;
    azib[(w + 4) * SW + slot] = pav * zi1;
    if (w == 0) { slot2e[slot] = e; slot2pa[slot] = pav; }
    int p1c = 4 * GP - np;
    if (e < 4) {
        int psl = (e < p1c) ? (np + e) : (4 * GP + 64 - np + (e - p1c));
        azib[w * SW + psl] = 0.f; azib[(w + 4) * SW + psl] = 0.f;
        if (w == 0) { slot2e[psl] = 0; slot2pa[psl] = 0.f; }
    }
    __syncthreads();

    // azjB blocked write: [bh][js][g][jl] float4 (4 consecutive slots per j)
    if (t < 8 * 17) {
        int r = t / 17, g = t % 17;
        float4 v;
        v.x = slot2pa[4 * g + 0] * tzj[r][slot2e[4 * g + 0]];
        v.y = slot2pa[4 * g + 1] * tzj[r][slot2e[4 * g + 1]];
        v.z = slot2pa[4 * g + 2] * tzj[r][slot2e[4 * g + 2]];
        v.w = slot2pa[4 * g + 3] * tzj[r][slot2e[4 * g + 3]];
        int jt = n0 >> 6, jl = (n0 & 63) + r;
        ((float4*)azjB)[((size_t)(bh * 8 + jt) * 17 + g) * 64 + jl] = v;
    }
}

// ---------------------------------------------------------------------------
// attn3: tile [16 i][64 j] per block, no jt loop, 2 barriers.
// grid = 2048 blocks x 256 thr (XCD-swizzled: one bh per XCD).
// wave w owns i-rows 4w..4w+3. PV loop-interchanged (h-read shared x4 rows).
// ---------------------------------------------------------------------------
__global__ __launch_bounds__(256, 4) void attn3(
    const float* __restrict__ h_ws, const float* __restrict__ azi_ws,
    const float* __restrict__ azjB, const float* __restrict__ adi_ws,
    const float* __restrict__ adj_ws, const float* __restrict__ a,
    float* __restrict__ pacc, float* __restrict__ pm, float* __restrict__ ps)
{
    // XCD-aware swizzle: orig%8 = XCD; give each XCD one contiguous 256-chunk
    int wg = (blockIdx.x & 7) * 256 + (blockIdx.x >> 3);
    int bh = wg >> 8, js = (wg >> 5) & 7, it = wg & 31;
    int i0 = it << 4, j0 = js << 6;
    int hh = bh & 3;

    __shared__ float htile[64 * 64];   // 16 KB
    __shared__ float azis[16 * SW];    // 4.35 KB
    __shared__ float pbuf[16][64];     // 4 KB

    int t = threadIdx.x, lane = t & 63;
    int w = __builtin_amdgcn_readfirstlane(t >> 6);

    // ---- stage (coalesced) ----
    {
        const float4* hsrc = (const float4*)(h_ws + ((size_t)bh * NN + j0) * DD);
        float4* hdst = (float4*)htile;
        #pragma unroll
        for (int k = 0; k < 4; ++k) hdst[t + 256 * k] = hsrc[t + 256 * k];
        const float4* zsrc = (const float4*)(azi_ws + ((size_t)bh * NN + i0) * SW);
        float4* zdst = (float4*)azis;
        zdst[t] = zsrc[t];
        if (t < 16) zdst[256 + t] = zsrc[256 + t];
    }

    // azj row for this lane -> regs (17 coalesced b128; shared across waves)
    float4 azj[17];
    {
        const float4* ajB = (const float4*)azjB
                          + ((size_t)(bh * 8 + js) * 17) * 64 + lane;
        #pragma unroll
        for (int k = 0; k < 17; ++k) azj[k] = ajB[k * 64];
    }
    float adjv = adj_ws[bh * NN + j0 + lane];

    // group-count from ballot of a (lane = e)
    float av_e = a[hh * DD + lane];
    unsigned long long mask = __ballot(av_e >= 0.f);
    int GP = (__popcll(mask) + 3) >> 2;

    int r0 = i0 + 4 * w;
    float adi0 = adi_ws[bh * NN + r0 + 0];
    float adi1 = adi_ws[bh * NN + r0 + 1];
    float adi2 = adi_ws[bh * NN + r0 + 2];
    float adi3 = adi_ws[bh * NN + r0 + 3];

    __syncthreads();

    // ---- scores + softmax partial for own 4 rows ----
    #pragma unroll
    for (int ii = 0; ii < 4; ++ii) {
        int i = 4 * w + ii;
        const float4* arow = (const float4*)(azis + i * SW);
        float c0 = 0.f, c1 = 0.f, c2 = 0.f, c3 = 0.f;
        #pragma unroll
        for (int k = 0; k < 17; ++k) {
            float4 zi4 = arow[k];              // uniform b128 broadcast
            float4 aj = azj[k];                // regs
            float s = (k < GP) ? 0.4f : -0.4f;
            c0 = fmaf(s, __builtin_fabsf(zi4.x + aj.x), c0);
            c1 = fmaf(s, __builtin_fabsf(zi4.y + aj.y), c1);
            c2 = fmaf(s, __builtin_fabsf(zi4.z + aj.z), c2);
            c3 = fmaf(s, __builtin_fabsf(zi4.w + aj.w), c3);
        }
        float adiv = (ii == 0) ? adi0 : (ii == 1) ? adi1 : (ii == 2) ? adi2 : adi3;
        float ev = adiv + adjv + ((c0 + c1) + (c2 + c3));
        float m = ev;
        #pragma unroll
        for (int off = 32; off; off >>= 1) m = fmaxf(m, __shfl_xor(m, off));
        float p = __expf(ev - m);
        float s = p;
        #pragma unroll
        for (int off = 32; off; off >>= 1) s += __shfl_xor(s, off);
        pbuf[i][lane] = p;
        if (lane == 0) {
            pm[js * 4096 + bh * NN + i0 + i] = m;   // FIXED: + i0
            ps[js * 4096 + bh * NN + i0 + i] = s;   // FIXED: + i0
        }
    }

    // ---- PV (interchanged: each h-read feeds 4 rows); pbuf wave-private ----
    float a0 = 0.f, a1 = 0.f, a2 = 0.f, a3 = 0.f;
    #pragma unroll
    for (int k = 0; k < 16; ++k) {
        float h0 = htile[(4 * k + 0) * 64 + lane];
        float h1 = htile[(4 * k + 1) * 64 + lane];
        float h2 = htile[(4 * k + 2) * 64 + lane];
        float h3 = htile[(4 * k + 3) * 64 + lane];
        float4 p0 = *(const float4*)&pbuf[4 * w + 0][4 * k];
        float4 p1 = *(const float4*)&pbuf[4 * w + 1][4 * k];
        float4 p2 = *(const float4*)&pbuf[4 * w + 2][4 * k];
        float4 p3 = *(const float4*)&pbuf[4 * w + 3][4 * k];
        a0 = fmaf(p0.x, h0, a0); a1 = fmaf(p1.x, h0, a1);
        a2 = fmaf(p2.x, h0, a2); a3 = fmaf(p3.x, h0, a3);
        a0 = fmaf(p0.y, h1, a0); a1 = fmaf(p1.y, h1, a1);
        a2 = fmaf(p2.y, h1, a2); a3 = fmaf(p3.y, h1, a3);
        a0 = fmaf(p0.z, h2, a0); a1 = fmaf(p1.z, h2, a1);
        a2 = fmaf(p2.z, h2, a2); a3 = fmaf(p3.z, h2, a3);
        a0 = fmaf(p0.w, h3, a0); a1 = fmaf(p1.w, h3, a1);
        a2 = fmaf(p2.w, h3, a2); a3 = fmaf(p3.w, h3, a3);
    }

    size_t ob = (size_t)js * 262144 + ((size_t)bh * NN + r0) * DD + lane;
    pacc[ob]          = a0;
    pacc[ob + DD]     = a1;
    pacc[ob + 2 * DD] = a2;
    pacc[ob + 3 * DD] = a3;
}

// ---------------------------------------------------------------------------
// combine 8 j-splits + bias. grid = 1024 x 256. (validated r4-r6)
// ---------------------------------------------------------------------------
__global__ __launch_bounds__(256) void combine_kernel(
    const float* __restrict__ pacc, const float* __restrict__ pm,
    const float* __restrict__ ps, const float* __restrict__ bias_param,
    float* __restrict__ out)
{
    int tid = blockIdx.x * 256 + threadIdx.x;
    int d = tid & 63;
    int row = tid >> 6;                 // bh*512 + n, 4096 rows
    int bh = row >> 9, n = row & 511;
    int b = bh >> 2, hh = bh & 3;
    float mv[8];
    float m = -1e30f;
    #pragma unroll
    for (int p = 0; p < 8; ++p) { mv[p] = pm[p * 4096 + row]; m = fmaxf(m, mv[p]); }
    float denom = 0.f, acc = 0.f;
    #pragma unroll
    for (int p = 0; p < 8; ++p) {
        float wgt = __expf(mv[p] - m);
        denom = fmaf(ps[p * 4096 + row], wgt, denom);
        acc = fmaf(pacc[(size_t)p * 262144 + (size_t)row * 64 + d], wgt, acc);
    }
    out[((size_t)b * NN + n) * (HH * DD) + hh * DD + d] =
        acc / denom + bias_param[hh * DD + d];
}

extern "C" void kernel_launch(void* const* d_in, const int* in_sizes, int n_in,
                              void* d_out, int out_size, void* d_ws, size_t ws_size,
                              hipStream_t stream) {
    const float* x    = (const float*)d_in[0];
    const float* Wp   = (const float*)d_in[1];
    const float* bp   = (const float*)d_in[2];
    const float* Wc   = (const float*)d_in[3];
    const float* Wcb  = (const float*)d_in[4];
    const float* a    = (const float*)d_in[5];
    const float* bpar = (const float*)d_in[6];
    float* out = (float*)d_out;

    float* ws     = (float*)d_ws;
    float* h_ws   = ws;
    float* azi_ws = ws + 262144;
    float* azjB   = ws + 540672;
    float* adi_ws = ws + 819200;
    float* adj_ws = ws + 823296;
    float* pacc   = ws + 827392;
    float* pm     = ws + 2924544;
    float* ps     = ws + 2957312;

    proj_kernel<<<dim3(512), dim3(256), 0, stream>>>(
        x, Wp, bp, Wc, Wcb, a, h_ws, azi_ws, azjB, adi_ws, adj_ws);
    attn3<<<dim3(2048), dim3(256), 0, stream>>>(
        h_ws, azi_ws, azjB, adi_ws, adj_ws, a, pacc, pm, ps);
    combine_kernel<<<dim3(1024), dim3(256), 0, stream>>>(
        pacc, pm, ps, bpar, out);
}